// Round 2
// baseline (692.044 us; speedup 1.0000x reference)
//
#include <hip/hip_runtime.h>
#include <math.h>

#define N_NODES 100000
#define N_EDGES 1600000
#define LN_EPS 1e-5f
#define NORM_EPS 1e-12f

// ---------------------------------------------------------------------------
// K1: h = x @ W^T + b  (N x 64), plus per-node attention scores
//     s_src[i][hd] = dot(h[i][hd], a[hd][0:8]) ; s_dst uses a[hd][8:16]
// ---------------------------------------------------------------------------
__global__ __launch_bounds__(256) void k_gemm(
    const float* __restrict__ x, const float* __restrict__ W,
    const float* __restrict__ b, const float* __restrict__ a,
    float* __restrict__ h, float* __restrict__ s_src, float* __restrict__ s_dst)
{
    __shared__ float WL[64 * 65];   // WL[k*65 + c] = W[c*64 + k]
    __shared__ float xs[16 * 64];
    const int tid  = threadIdx.x;
    const int lane = tid & 63;
    const int wv   = tid >> 6;

    for (int idx = tid; idx < 64 * 64; idx += 256) {
        int c = idx >> 6, k = idx & 63;
        WL[k * 65 + c] = W[idx];
    }
    const int row0 = blockIdx.x * 16;
    for (int idx = tid; idx < 16 * 64; idx += 256) {
        int r = row0 + (idx >> 6);
        xs[idx] = (r < N_NODES) ? x[(size_t)r * 64 + (idx & 63)] : 0.f;
    }
    __syncthreads();

    const float asrc = a[(lane >> 3) * 16 + (lane & 7)];
    const float adst = a[(lane >> 3) * 16 + 8 + (lane & 7)];
    const float bias = b[lane];

    float sum0 = 0.f, sum1 = 0.f, sum2 = 0.f, sum3 = 0.f;
    const int rbase = wv * 4;
    #pragma unroll
    for (int k = 0; k < 64; ++k) {
        float wk = WL[k * 65 + lane];
        sum0 += xs[(rbase + 0) * 64 + k] * wk;
        sum1 += xs[(rbase + 1) * 64 + k] * wk;
        sum2 += xs[(rbase + 2) * 64 + k] * wk;
        sum3 += xs[(rbase + 3) * 64 + k] * wk;
    }
    float sums[4] = {sum0 + bias, sum1 + bias, sum2 + bias, sum3 + bias};
    #pragma unroll
    for (int j = 0; j < 4; ++j) {
        int r = row0 + rbase + j;
        if (r >= N_NODES) break;
        float v = sums[j];
        h[(size_t)r * 64 + lane] = v;
        float p = v * asrc, q = v * adst;
        p += __shfl_xor(p, 1);  q += __shfl_xor(q, 1);
        p += __shfl_xor(p, 2);  q += __shfl_xor(q, 2);
        p += __shfl_xor(p, 4);  q += __shfl_xor(q, 4);
        if ((lane & 7) == 0) {
            s_src[r * 8 + (lane >> 3)] = p;
            s_dst[r * 8 + (lane >> 3)] = q;
        }
    }
}

// ---------------------------------------------------------------------------
// CSR build: count out-degree per src
// ---------------------------------------------------------------------------
__global__ __launch_bounds__(256) void k_count(
    const int* __restrict__ ei, int* __restrict__ counts)
{
    int e = blockIdx.x * 256 + threadIdx.x;
    if (e < N_EDGES) atomicAdd(&counts[ei[e]], 1);
}

// ---------------------------------------------------------------------------
// Single-block exclusive scan over counts -> row_ptr (and a cursor copy).
// 1024 threads (16 waves), 98 tiles of 1024.
// ---------------------------------------------------------------------------
__global__ __launch_bounds__(1024) void k_scan(
    const int* __restrict__ counts, int* __restrict__ row_ptr,
    int* __restrict__ cursor)
{
    __shared__ int wsum[16];
    __shared__ int carry;
    const int tid = threadIdx.x;
    const int lane = tid & 63;
    const int wv = tid >> 6;
    if (tid == 0) carry = 0;
    __syncthreads();

    for (int base = 0; base < N_NODES; base += 1024) {
        int i = base + tid;
        int v = (i < N_NODES) ? counts[i] : 0;
        // inclusive scan within wave
        int sc = v;
        #pragma unroll
        for (int off = 1; off < 64; off <<= 1) {
            int t = __shfl_up(sc, off);
            if (lane >= off) sc += t;
        }
        if (lane == 63) wsum[wv] = sc;
        __syncthreads();
        if (tid < 16) {
            int ws = wsum[tid];
            #pragma unroll
            for (int off = 1; off < 16; off <<= 1) {
                int t = __shfl_up(ws, off);
                if (tid >= off) ws += t;
            }
            wsum[tid] = ws;   // inclusive scan of wave sums
        }
        __syncthreads();
        int pref = carry + (wv ? wsum[wv - 1] : 0);
        int excl = pref + sc - v;
        if (i < N_NODES) { row_ptr[i] = excl; cursor[i] = excl; }
        __syncthreads();
        if (tid == 0) carry += wsum[15];
        __syncthreads();
    }
    if (threadIdx.x == 0) row_ptr[N_NODES] = carry;
}

// ---------------------------------------------------------------------------
// Fill: scatter dst ids into CSR slots
// ---------------------------------------------------------------------------
__global__ __launch_bounds__(256) void k_fill(
    const int* __restrict__ ei, int* __restrict__ cursor,
    int* __restrict__ dst_sorted)
{
    int e = blockIdx.x * 256 + threadIdx.x;
    if (e >= N_EDGES) return;
    int src = ei[e];
    int dst = ei[N_EDGES + e];
    int slot = atomicAdd(&cursor[src], 1);
    dst_sorted[slot] = dst;
}

// ---------------------------------------------------------------------------
// Gather + epilogue: one wave per node.  lane = dim, head = lane>>3.
// acc = sum over out-edges of alpha*h[dst]; then residual + LN + L2 norm.
// ---------------------------------------------------------------------------
__global__ __launch_bounds__(256) void k_gather(
    const int* __restrict__ row_ptr, const int* __restrict__ dst_sorted,
    const float* __restrict__ h, const float* __restrict__ s_src,
    const float* __restrict__ s_dst, const float* __restrict__ x,
    const float* __restrict__ ln_scale, const float* __restrict__ ln_bias,
    float* __restrict__ out)
{
    const int i = blockIdx.x * 4 + (threadIdx.x >> 6);
    if (i >= N_NODES) return;
    const int lane = threadIdx.x & 63;
    const int head = lane >> 3;

    const int beg = row_ptr[i];
    const int end = row_ptr[i + 1];
    const float ssrc = s_src[i * 8 + head];
    const float xres = x[(size_t)i * 64 + lane];   // early load, overlaps loop

    float acc = 0.f;
    int dst = (beg < end) ? dst_sorted[beg] : 0;
    for (int e = beg; e < end; ++e) {
        int dst_next = (e + 1 < end) ? dst_sorted[e + 1] : 0;  // prefetch
        float v = ssrc + s_dst[dst * 8 + head];
        v = (v >= 0.f) ? v : 0.2f * v;
        float m = v;
        m = fmaxf(m, __shfl_xor(m, 8));
        m = fmaxf(m, __shfl_xor(m, 16));
        m = fmaxf(m, __shfl_xor(m, 32));
        float ex = __expf(v - m);
        float s = ex;
        s += __shfl_xor(s, 8);
        s += __shfl_xor(s, 16);
        s += __shfl_xor(s, 32);
        acc += (ex / s) * h[(size_t)dst * 64 + lane];
        dst = dst_next;
    }

    // epilogue: residual + LayerNorm + L2 normalize
    float v = acc + xres;
    float s = v;
    #pragma unroll
    for (int off = 1; off < 64; off <<= 1) s += __shfl_xor(s, off);
    const float mu = s * (1.f / 64.f);
    const float d = v - mu;
    float vs = d * d;
    #pragma unroll
    for (int off = 1; off < 64; off <<= 1) vs += __shfl_xor(vs, off);
    const float var = vs * (1.f / 64.f);
    float y = d * rsqrtf(var + LN_EPS) * ln_scale[lane] + ln_bias[lane];
    float ss = y * y;
    #pragma unroll
    for (int off = 1; off < 64; off <<= 1) ss += __shfl_xor(ss, off);
    const float norm = sqrtf(ss);
    out[(size_t)i * 64 + lane] = y / fmaxf(norm, NORM_EPS);
}

// ---------------------------------------------------------------------------
extern "C" void kernel_launch(void* const* d_in, const int* in_sizes, int n_in,
                              void* d_out, int out_size, void* d_ws, size_t ws_size,
                              hipStream_t stream)
{
    const float* x        = (const float*)d_in[0];
    const int*   ei       = (const int*)d_in[1];
    const float* W        = (const float*)d_in[2];
    const float* b        = (const float*)d_in[3];
    const float* a        = (const float*)d_in[4];
    const float* ln_scale = (const float*)d_in[5];
    const float* ln_bias  = (const float*)d_in[6];
    float* out = (float*)d_out;

    char* ws = (char*)d_ws;
    size_t off = 0;
    float* h          = (float*)(ws + off); off += (size_t)N_NODES * 64 * 4;
    float* s_src      = (float*)(ws + off); off += (size_t)N_NODES * 8 * 4;
    float* s_dst      = (float*)(ws + off); off += (size_t)N_NODES * 8 * 4;
    int*   counts     = (int*)  (ws + off); off += (size_t)N_NODES * 4;
    int*   row_ptr    = (int*)  (ws + off); off += (size_t)(N_NODES + 1) * 4;
    int*   cursor     = (int*)  (ws + off); off += (size_t)N_NODES * 4;
    int*   dst_sorted = (int*)  (ws + off); off += (size_t)N_EDGES * 4;

    hipMemsetAsync(counts, 0, (size_t)N_NODES * 4, stream);

    k_gemm  <<<(N_NODES + 15) / 16,  256, 0, stream>>>(x, W, b, a, h, s_src, s_dst);
    k_count <<<(N_EDGES + 255) / 256, 256, 0, stream>>>(ei, counts);
    k_scan  <<<1, 1024, 0, stream>>>(counts, row_ptr, cursor);
    k_fill  <<<(N_EDGES + 255) / 256, 256, 0, stream>>>(ei, cursor, dst_sorted);
    k_gather<<<(N_NODES + 3) / 4,    256, 0, stream>>>(row_ptr, dst_sorted, h,
                                                       s_src, s_dst, x,
                                                       ln_scale, ln_bias, out);
}

// Round 3
// 533.019 us; speedup vs baseline: 1.2983x; 1.2983x over previous
//
#include <hip/hip_runtime.h>
#include <math.h>

#define N_NODES 100000
#define N_EDGES 1600000
#define LN_EPS 1e-5f
#define NORM_EPS 1e-12f
#define SCAN_TILE 1024
#define N_TILES ((N_NODES + SCAN_TILE - 1) / SCAN_TILE)   // 98

// bf16 helpers (round-to-nearest-even)
__device__ __forceinline__ unsigned short f2bf(float f) {
    unsigned int u = __float_as_uint(f);
    u += 0x7FFFu + ((u >> 16) & 1u);
    return (unsigned short)(u >> 16);
}
__device__ __forceinline__ float bf2f(unsigned short h) {
    return __uint_as_float(((unsigned int)h) << 16);
}

// ---------------------------------------------------------------------------
// K1: h = x @ W^T + b  (N x 64) -> stored bf16; plus per-node attn scores
//     s_src[i][hd] = dot(h[i][hd], a[hd][0:8]) ; s_dst uses a[hd][8:16]
// ---------------------------------------------------------------------------
__global__ __launch_bounds__(256) void k_gemm(
    const float* __restrict__ x, const float* __restrict__ W,
    const float* __restrict__ b, const float* __restrict__ a,
    unsigned short* __restrict__ h16,
    float* __restrict__ s_src, float* __restrict__ s_dst)
{
    __shared__ float WL[64 * 65];   // WL[k*65 + c] = W[c*64 + k]
    __shared__ float xs[16 * 64];
    const int tid  = threadIdx.x;
    const int lane = tid & 63;
    const int wv   = tid >> 6;

    for (int idx = tid; idx < 64 * 64; idx += 256) {
        int c = idx >> 6, k = idx & 63;
        WL[k * 65 + c] = W[idx];
    }
    const int row0 = blockIdx.x * 16;
    for (int idx = tid; idx < 16 * 64; idx += 256) {
        int r = row0 + (idx >> 6);
        xs[idx] = (r < N_NODES) ? x[(size_t)r * 64 + (idx & 63)] : 0.f;
    }
    __syncthreads();

    const float asrc = a[(lane >> 3) * 16 + (lane & 7)];
    const float adst = a[(lane >> 3) * 16 + 8 + (lane & 7)];
    const float bias = b[lane];

    float sum0 = 0.f, sum1 = 0.f, sum2 = 0.f, sum3 = 0.f;
    const int rbase = wv * 4;
    #pragma unroll
    for (int k = 0; k < 64; ++k) {
        float wk = WL[k * 65 + lane];
        sum0 += xs[(rbase + 0) * 64 + k] * wk;
        sum1 += xs[(rbase + 1) * 64 + k] * wk;
        sum2 += xs[(rbase + 2) * 64 + k] * wk;
        sum3 += xs[(rbase + 3) * 64 + k] * wk;
    }
    float sums[4] = {sum0 + bias, sum1 + bias, sum2 + bias, sum3 + bias};
    #pragma unroll
    for (int j = 0; j < 4; ++j) {
        int r = row0 + rbase + j;
        if (r >= N_NODES) break;
        float v = sums[j];
        h16[(size_t)r * 64 + lane] = f2bf(v);
        float p = v * asrc, q = v * adst;
        p += __shfl_xor(p, 1);  q += __shfl_xor(q, 1);
        p += __shfl_xor(p, 2);  q += __shfl_xor(q, 2);
        p += __shfl_xor(p, 4);  q += __shfl_xor(q, 4);
        if ((lane & 7) == 0) {
            s_src[r * 8 + (lane >> 3)] = p;
            s_dst[r * 8 + (lane >> 3)] = q;
        }
    }
}

// ---------------------------------------------------------------------------
// CSR build: count out-degree per src
// ---------------------------------------------------------------------------
__global__ __launch_bounds__(256) void k_count(
    const int* __restrict__ ei, int* __restrict__ counts)
{
    int e = blockIdx.x * 256 + threadIdx.x;
    if (e < N_EDGES) atomicAdd(&counts[ei[e]], 1);
}

// ---------------------------------------------------------------------------
// Multi-block scan, stage 1: per-tile exclusive scan + tile totals.
// ---------------------------------------------------------------------------
__global__ __launch_bounds__(1024) void k_scan1(
    const int* __restrict__ counts, int* __restrict__ row_ptr,
    int* __restrict__ blksum)
{
    __shared__ int wsum[16];
    const int tid = threadIdx.x, lane = tid & 63, wv = tid >> 6;
    const int i = blockIdx.x * SCAN_TILE + tid;
    int v = (i < N_NODES) ? counts[i] : 0;
    int sc = v;
    #pragma unroll
    for (int off = 1; off < 64; off <<= 1) {
        int t = __shfl_up(sc, off);
        if (lane >= off) sc += t;
    }
    if (lane == 63) wsum[wv] = sc;
    __syncthreads();
    if (tid < 16) {
        int ws = wsum[tid];
        #pragma unroll
        for (int off = 1; off < 16; off <<= 1) {
            int t = __shfl_up(ws, off);
            if (tid >= off) ws += t;
        }
        wsum[tid] = ws;
    }
    __syncthreads();
    const int pref = wv ? wsum[wv - 1] : 0;
    if (i < N_NODES) row_ptr[i] = pref + sc - v;   // tile-local exclusive
    if (tid == 0) blksum[blockIdx.x] = wsum[15];
}

// Stage 2: one wave scans the 98 tile totals (exclusive, in place).
__global__ __launch_bounds__(64) void k_scan2(
    int* __restrict__ blksum, int* __restrict__ row_ptr)
{
    const int tid = threadIdx.x;
    int carry = 0;
    for (int base = 0; base < N_TILES; base += 64) {
        int i = base + tid;
        int v = (i < N_TILES) ? blksum[i] : 0;
        int sc = v;
        #pragma unroll
        for (int off = 1; off < 64; off <<= 1) {
            int t = __shfl_up(sc, off);
            if (tid >= off) sc += t;
        }
        if (i < N_TILES) blksum[i] = carry + sc - v;
        carry += __shfl(sc, 63);
    }
    if (tid == 0) row_ptr[N_NODES] = carry;   // = N_EDGES
}

// Stage 3: add tile offsets, init cursor.
__global__ __launch_bounds__(256) void k_scan3(
    int* __restrict__ row_ptr, const int* __restrict__ blksum,
    int* __restrict__ cursor)
{
    int i = blockIdx.x * 256 + threadIdx.x;
    if (i < N_NODES) {
        int r = row_ptr[i] + blksum[i >> 10];
        row_ptr[i] = r;
        cursor[i] = r;
    }
}

// ---------------------------------------------------------------------------
// Fill: scatter dst ids into CSR slots
// ---------------------------------------------------------------------------
__global__ __launch_bounds__(256) void k_fill(
    const int* __restrict__ ei, int* __restrict__ cursor,
    int* __restrict__ dst_sorted)
{
    int e = blockIdx.x * 256 + threadIdx.x;
    if (e >= N_EDGES) return;
    int src = ei[e];
    int dst = ei[N_EDGES + e];
    int slot = atomicAdd(&cursor[src], 1);
    dst_sorted[slot] = dst;
}

// ---------------------------------------------------------------------------
// Gather + epilogue: one wave per node.  lane = dim, head = lane>>3.
// 2-way unrolled for memory-level parallelism; h in bf16 (128B/row).
// ---------------------------------------------------------------------------
__global__ __launch_bounds__(256) void k_gather(
    const int* __restrict__ row_ptr, const int* __restrict__ dst_sorted,
    const unsigned short* __restrict__ h16, const float* __restrict__ s_src,
    const float* __restrict__ s_dst, const float* __restrict__ x,
    const float* __restrict__ ln_scale, const float* __restrict__ ln_bias,
    float* __restrict__ out)
{
    const int i = blockIdx.x * 4 + (threadIdx.x >> 6);
    if (i >= N_NODES) return;
    const int lane = threadIdx.x & 63;
    const int head = lane >> 3;

    const int beg = row_ptr[i];
    const int end = row_ptr[i + 1];
    const float ssrc = s_src[i * 8 + head];
    const float xres = x[(size_t)i * 64 + lane];

    float acc = 0.f;
    int e = beg;
    for (; e + 1 < end; e += 2) {
        const int dA = dst_sorted[e];
        const int dB = dst_sorted[e + 1];
        const float sdA = s_dst[dA * 8 + head];
        const float sdB = s_dst[dB * 8 + head];
        const unsigned short hA = h16[(size_t)dA * 64 + lane];
        const unsigned short hB = h16[(size_t)dB * 64 + lane];

        float vA = ssrc + sdA; vA = (vA >= 0.f) ? vA : 0.2f * vA;
        float vB = ssrc + sdB; vB = (vB >= 0.f) ? vB : 0.2f * vB;
        float mA = vA, mB = vB;
        mA = fmaxf(mA, __shfl_xor(mA, 8));   mB = fmaxf(mB, __shfl_xor(mB, 8));
        mA = fmaxf(mA, __shfl_xor(mA, 16));  mB = fmaxf(mB, __shfl_xor(mB, 16));
        mA = fmaxf(mA, __shfl_xor(mA, 32));  mB = fmaxf(mB, __shfl_xor(mB, 32));
        float eA = __expf(vA - mA), eB = __expf(vB - mB);
        float sA = eA, sB = eB;
        sA += __shfl_xor(sA, 8);   sB += __shfl_xor(sB, 8);
        sA += __shfl_xor(sA, 16);  sB += __shfl_xor(sB, 16);
        sA += __shfl_xor(sA, 32);  sB += __shfl_xor(sB, 32);
        acc += eA * __builtin_amdgcn_rcpf(sA) * bf2f(hA);
        acc += eB * __builtin_amdgcn_rcpf(sB) * bf2f(hB);
    }
    if (e < end) {
        const int d = dst_sorted[e];
        float v = ssrc + s_dst[d * 8 + head];
        v = (v >= 0.f) ? v : 0.2f * v;
        float m = v;
        m = fmaxf(m, __shfl_xor(m, 8));
        m = fmaxf(m, __shfl_xor(m, 16));
        m = fmaxf(m, __shfl_xor(m, 32));
        float ex = __expf(v - m);
        float s = ex;
        s += __shfl_xor(s, 8);
        s += __shfl_xor(s, 16);
        s += __shfl_xor(s, 32);
        acc += ex * __builtin_amdgcn_rcpf(s) * bf2f(h16[(size_t)d * 64 + lane]);
    }

    // epilogue: residual + LayerNorm + L2 normalize
    float v = acc + xres;
    float s = v;
    #pragma unroll
    for (int off = 1; off < 64; off <<= 1) s += __shfl_xor(s, off);
    const float mu = s * (1.f / 64.f);
    const float d = v - mu;
    float vs = d * d;
    #pragma unroll
    for (int off = 1; off < 64; off <<= 1) vs += __shfl_xor(vs, off);
    const float var = vs * (1.f / 64.f);
    float y = d * rsqrtf(var + LN_EPS) * ln_scale[lane] + ln_bias[lane];
    float ss = y * y;
    #pragma unroll
    for (int off = 1; off < 64; off <<= 1) ss += __shfl_xor(ss, off);
    const float norm = sqrtf(ss);
    out[(size_t)i * 64 + lane] = y / fmaxf(norm, NORM_EPS);
}

// ---------------------------------------------------------------------------
extern "C" void kernel_launch(void* const* d_in, const int* in_sizes, int n_in,
                              void* d_out, int out_size, void* d_ws, size_t ws_size,
                              hipStream_t stream)
{
    const float* x        = (const float*)d_in[0];
    const int*   ei       = (const int*)d_in[1];
    const float* W        = (const float*)d_in[2];
    const float* b        = (const float*)d_in[3];
    const float* a        = (const float*)d_in[4];
    const float* ln_scale = (const float*)d_in[5];
    const float* ln_bias  = (const float*)d_in[6];
    float* out = (float*)d_out;

    char* ws = (char*)d_ws;
    size_t off = 0;
    unsigned short* h16 = (unsigned short*)(ws + off); off += (size_t)N_NODES * 64 * 2;
    off = (off + 255) & ~(size_t)255;
    float* s_src      = (float*)(ws + off); off += (size_t)N_NODES * 8 * 4;
    float* s_dst      = (float*)(ws + off); off += (size_t)N_NODES * 8 * 4;
    int*   counts     = (int*)  (ws + off); off += (size_t)N_NODES * 4;
    int*   row_ptr    = (int*)  (ws + off); off += (size_t)(N_NODES + 1) * 4;
    int*   cursor     = (int*)  (ws + off); off += (size_t)N_NODES * 4;
    int*   blksum     = (int*)  (ws + off); off += (size_t)N_TILES * 4;
    off = (off + 255) & ~(size_t)255;
    int*   dst_sorted = (int*)  (ws + off); off += (size_t)N_EDGES * 4;

    hipMemsetAsync(counts, 0, (size_t)N_NODES * 4, stream);

    k_gemm  <<<(N_NODES + 15) / 16,   256, 0, stream>>>(x, W, b, a, h16, s_src, s_dst);
    k_count <<<(N_EDGES + 255) / 256, 256, 0, stream>>>(ei, counts);
    k_scan1 <<<N_TILES, 1024, 0, stream>>>(counts, row_ptr, blksum);
    k_scan2 <<<1, 64, 0, stream>>>(blksum, row_ptr);
    k_scan3 <<<(N_NODES + 255) / 256, 256, 0, stream>>>(row_ptr, blksum, cursor);
    k_fill  <<<(N_EDGES + 255) / 256, 256, 0, stream>>>(ei, cursor, dst_sorted);
    k_gather<<<(N_NODES + 3) / 4,     256, 0, stream>>>(row_ptr, dst_sorted, h16,
                                                        s_src, s_dst, x,
                                                        ln_scale, ln_bias, out);
}

// Round 4
// 374.101 us; speedup vs baseline: 1.8499x; 1.4248x over previous
//
#include <hip/hip_runtime.h>
#include <math.h>

#define N_NODES 100000
#define N_EDGES 1600000
#define LN_EPS 1e-5f
#define NORM_EPS 1e-12f
#define SCAN_TILE 1024
#define N_TILES ((N_NODES + SCAN_TILE - 1) / SCAN_TILE)   // 98

// bf16 helpers (round-to-nearest-even)
__device__ __forceinline__ unsigned short f2bf(float f) {
    unsigned int u = __float_as_uint(f);
    u += 0x7FFFu + ((u >> 16) & 1u);
    return (unsigned short)(u >> 16);
}
__device__ __forceinline__ float bf2f(unsigned short h) {
    return __uint_as_float(((unsigned int)h) << 16);
}

// ---------------------------------------------------------------------------
// K1: h = x @ W^T + b (N x 64) -> bf16; per-node attn scores s_src/s_dst;
// PLUS fused out-degree count (this grid's 1.6M threads exactly cover E).
// ---------------------------------------------------------------------------
__global__ __launch_bounds__(256) void k_gemm(
    const float* __restrict__ x, const float* __restrict__ W,
    const float* __restrict__ b, const float* __restrict__ a,
    const int* __restrict__ ei, int* __restrict__ counts,
    unsigned short* __restrict__ h16,
    float* __restrict__ s_src, float* __restrict__ s_dst)
{
    __shared__ float WL[64 * 65];   // WL[k*65 + c] = W[c*64 + k]
    __shared__ float xs[16 * 64];
    const int tid  = threadIdx.x;
    const int lane = tid & 63;
    const int wv   = tid >> 6;

    // fused edge count: one thread per edge (grid = 6250*256 = 1.6M = E)
    {
        const int e = blockIdx.x * 256 + tid;
        if (e < N_EDGES) atomicAdd(&counts[ei[e]], 1);
    }

    // stage W transposed (vectorized reads)
    for (int idx = tid * 4; idx < 64 * 64; idx += 256 * 4) {
        float4 w = *(const float4*)(W + idx);
        int c = idx >> 6, k = idx & 63;
        WL[(k + 0) * 65 + c] = w.x;
        WL[(k + 1) * 65 + c] = w.y;
        WL[(k + 2) * 65 + c] = w.z;
        WL[(k + 3) * 65 + c] = w.w;
    }
    const int row0 = blockIdx.x * 16;
    for (int idx = tid * 4; idx < 16 * 64; idx += 256 * 4) {
        int r = row0 + (idx >> 6);
        float4 v = (r < N_NODES) ? *(const float4*)(x + (size_t)r * 64 + (idx & 63))
                                 : make_float4(0.f, 0.f, 0.f, 0.f);
        *(float4*)(xs + idx) = v;
    }
    __syncthreads();

    const float asrc = a[(lane >> 3) * 16 + (lane & 7)];
    const float adst = a[(lane >> 3) * 16 + 8 + (lane & 7)];
    const float bias = b[lane];

    float sum0 = 0.f, sum1 = 0.f, sum2 = 0.f, sum3 = 0.f;
    const int rbase = wv * 4;
    #pragma unroll
    for (int k = 0; k < 64; ++k) {
        float wk = WL[k * 65 + lane];
        sum0 += xs[(rbase + 0) * 64 + k] * wk;
        sum1 += xs[(rbase + 1) * 64 + k] * wk;
        sum2 += xs[(rbase + 2) * 64 + k] * wk;
        sum3 += xs[(rbase + 3) * 64 + k] * wk;
    }
    float sums[4] = {sum0 + bias, sum1 + bias, sum2 + bias, sum3 + bias};
    #pragma unroll
    for (int j = 0; j < 4; ++j) {
        int r = row0 + rbase + j;
        if (r >= N_NODES) break;
        float v = sums[j];
        h16[(size_t)r * 64 + lane] = f2bf(v);
        float p = v * asrc, q = v * adst;
        p += __shfl_xor(p, 1);  q += __shfl_xor(q, 1);
        p += __shfl_xor(p, 2);  q += __shfl_xor(q, 2);
        p += __shfl_xor(p, 4);  q += __shfl_xor(q, 4);
        if ((lane & 7) == 0) {
            s_src[r * 8 + (lane >> 3)] = p;
            s_dst[r * 8 + (lane >> 3)] = q;
        }
    }
}

// ---------------------------------------------------------------------------
// Scan stage 1: per-tile (1024) exclusive scan + tile totals.
// ---------------------------------------------------------------------------
__global__ __launch_bounds__(1024) void k_scan1(
    const int* __restrict__ counts, int* __restrict__ row_ptr,
    int* __restrict__ blksum)
{
    __shared__ int wsum[16];
    const int tid = threadIdx.x, lane = tid & 63, wv = tid >> 6;
    const int i = blockIdx.x * SCAN_TILE + tid;
    int v = (i < N_NODES) ? counts[i] : 0;
    int sc = v;
    #pragma unroll
    for (int off = 1; off < 64; off <<= 1) {
        int t = __shfl_up(sc, off);
        if (lane >= off) sc += t;
    }
    if (lane == 63) wsum[wv] = sc;
    __syncthreads();
    if (tid < 16) {
        int ws = wsum[tid];
        #pragma unroll
        for (int off = 1; off < 16; off <<= 1) {
            int t = __shfl_up(ws, off);
            if (tid >= off) ws += t;
        }
        wsum[tid] = ws;
    }
    __syncthreads();
    const int pref = wv ? wsum[wv - 1] : 0;
    if (i < N_NODES) row_ptr[i] = pref + sc - v;   // tile-local exclusive
    if (tid == 0) blksum[blockIdx.x] = wsum[15];
}

// ---------------------------------------------------------------------------
// Scan stages 2+3 fused: each block redundantly scans the 98 tile totals
// in its first wave, then adds the tile offset and inits cursor.
// ---------------------------------------------------------------------------
__global__ __launch_bounds__(256) void k_scan23(
    int* __restrict__ row_ptr, const int* __restrict__ blksum,
    int* __restrict__ cursor)
{
    __shared__ int spref[N_TILES];
    const int tid = threadIdx.x;
    if (tid < 64) {
        int v0 = (tid < N_TILES) ? blksum[tid] : 0;
        int s0 = v0;
        #pragma unroll
        for (int off = 1; off < 64; off <<= 1) {
            int t = __shfl_up(s0, off);
            if (tid >= off) s0 += t;
        }
        if (tid < N_TILES) spref[tid] = s0 - v0;
        int carry = __shfl(s0, 63);
        int i2 = 64 + tid;
        int v1 = (i2 < N_TILES) ? blksum[i2] : 0;
        int s1 = v1;
        #pragma unroll
        for (int off = 1; off < 64; off <<= 1) {
            int t = __shfl_up(s1, off);
            if (tid >= off) s1 += t;
        }
        if (i2 < N_TILES) spref[i2] = carry + s1 - v1;
    }
    __syncthreads();
    const int i = blockIdx.x * 256 + tid;
    if (i < N_NODES) {
        int r = row_ptr[i] + spref[i >> 10];
        row_ptr[i] = r;
        cursor[i] = r;
    }
    if (i == 0) row_ptr[N_NODES] = N_EDGES;
}

// ---------------------------------------------------------------------------
// Fill + alpha: one THREAD per edge.  Scatter dst into CSR slot and compute
// the full 8-head softmax once (not 64 redundant lane copies) -> alpha8.
// ---------------------------------------------------------------------------
__global__ __launch_bounds__(256) void k_fill_alpha(
    const int* __restrict__ ei, int* __restrict__ cursor,
    const float* __restrict__ s_src, const float* __restrict__ s_dst,
    int* __restrict__ dst_sorted, float* __restrict__ alpha8)
{
    const int e = blockIdx.x * 256 + threadIdx.x;
    if (e >= N_EDGES) return;
    const int src = ei[e];
    const int dst = ei[N_EDGES + e];
    const int slot = atomicAdd(&cursor[src], 1);
    dst_sorted[slot] = dst;

    const float4 a0 = *(const float4*)(s_src + (size_t)src * 8);
    const float4 a1 = *(const float4*)(s_src + (size_t)src * 8 + 4);
    const float4 b0 = *(const float4*)(s_dst + (size_t)dst * 8);
    const float4 b1 = *(const float4*)(s_dst + (size_t)dst * 8 + 4);
    float sc[8] = {a0.x + b0.x, a0.y + b0.y, a0.z + b0.z, a0.w + b0.w,
                   a1.x + b1.x, a1.y + b1.y, a1.z + b1.z, a1.w + b1.w};
    float m = -1e30f;
    #pragma unroll
    for (int h = 0; h < 8; ++h) {
        sc[h] = (sc[h] >= 0.f) ? sc[h] : 0.2f * sc[h];
        m = fmaxf(m, sc[h]);
    }
    float sum = 0.f;
    #pragma unroll
    for (int h = 0; h < 8; ++h) { sc[h] = __expf(sc[h] - m); sum += sc[h]; }
    const float inv = 1.f / sum;
    float4 o0 = make_float4(sc[0] * inv, sc[1] * inv, sc[2] * inv, sc[3] * inv);
    float4 o1 = make_float4(sc[4] * inv, sc[5] * inv, sc[6] * inv, sc[7] * inv);
    *(float4*)(alpha8 + (size_t)slot * 8)     = o0;
    *(float4*)(alpha8 + (size_t)slot * 8 + 4) = o1;
}

// ---------------------------------------------------------------------------
// Gather + epilogue: one wave per node; slim inner loop (alpha precomputed).
// ---------------------------------------------------------------------------
__global__ __launch_bounds__(256) void k_gather(
    const int* __restrict__ row_ptr, const int* __restrict__ dst_sorted,
    const float* __restrict__ alpha8, const unsigned short* __restrict__ h16,
    const float* __restrict__ x, const float* __restrict__ ln_scale,
    const float* __restrict__ ln_bias, float* __restrict__ out)
{
    const int i = blockIdx.x * 4 + (threadIdx.x >> 6);
    if (i >= N_NODES) return;
    const int lane = threadIdx.x & 63;
    const int head = lane >> 3;

    const int beg = row_ptr[i];
    const int end = row_ptr[i + 1];
    const float xres = x[(size_t)i * 64 + lane];

    float acc = 0.f;
    int e = beg;
    for (; e + 3 < end; e += 4) {
        const int d0 = dst_sorted[e];
        const int d1 = dst_sorted[e + 1];
        const int d2 = dst_sorted[e + 2];
        const int d3 = dst_sorted[e + 3];
        const float al0 = alpha8[(size_t)(e + 0) * 8 + head];
        const float al1 = alpha8[(size_t)(e + 1) * 8 + head];
        const float al2 = alpha8[(size_t)(e + 2) * 8 + head];
        const float al3 = alpha8[(size_t)(e + 3) * 8 + head];
        const float h0 = bf2f(h16[(size_t)d0 * 64 + lane]);
        const float h1 = bf2f(h16[(size_t)d1 * 64 + lane]);
        const float h2 = bf2f(h16[(size_t)d2 * 64 + lane]);
        const float h3 = bf2f(h16[(size_t)d3 * 64 + lane]);
        acc += al0 * h0 + al1 * h1 + al2 * h2 + al3 * h3;
    }
    for (; e < end; ++e)
        acc += alpha8[(size_t)e * 8 + head] *
               bf2f(h16[(size_t)dst_sorted[e] * 64 + lane]);

    // epilogue: residual + LayerNorm + L2 normalize
    float v = acc + xres;
    float s = v;
    #pragma unroll
    for (int off = 1; off < 64; off <<= 1) s += __shfl_xor(s, off);
    const float mu = s * (1.f / 64.f);
    const float d = v - mu;
    float vs = d * d;
    #pragma unroll
    for (int off = 1; off < 64; off <<= 1) vs += __shfl_xor(vs, off);
    const float var = vs * (1.f / 64.f);
    float y = d * rsqrtf(var + LN_EPS) * ln_scale[lane] + ln_bias[lane];
    float ss = y * y;
    #pragma unroll
    for (int off = 1; off < 64; off <<= 1) ss += __shfl_xor(ss, off);
    const float norm = sqrtf(ss);
    out[(size_t)i * 64 + lane] = y / fmaxf(norm, NORM_EPS);
}

// ---------------------------------------------------------------------------
extern "C" void kernel_launch(void* const* d_in, const int* in_sizes, int n_in,
                              void* d_out, int out_size, void* d_ws, size_t ws_size,
                              hipStream_t stream)
{
    const float* x        = (const float*)d_in[0];
    const int*   ei       = (const int*)d_in[1];
    const float* W        = (const float*)d_in[2];
    const float* b        = (const float*)d_in[3];
    const float* a        = (const float*)d_in[4];
    const float* ln_scale = (const float*)d_in[5];
    const float* ln_bias  = (const float*)d_in[6];
    float* out = (float*)d_out;

    char* ws = (char*)d_ws;
    size_t off = 0;
    auto alloc = [&](size_t bytes) {
        void* p = ws + off;
        off = (off + bytes + 255) & ~(size_t)255;
        return p;
    };
    unsigned short* h16 = (unsigned short*)alloc((size_t)N_NODES * 64 * 2);
    float* s_src      = (float*)alloc((size_t)N_NODES * 8 * 4);
    float* s_dst      = (float*)alloc((size_t)N_NODES * 8 * 4);
    int*   counts     = (int*)  alloc((size_t)N_NODES * 4);
    int*   row_ptr    = (int*)  alloc((size_t)(N_NODES + 1) * 4);
    int*   cursor     = (int*)  alloc((size_t)N_NODES * 4);
    int*   blksum     = (int*)  alloc((size_t)N_TILES * 4);
    int*   dst_sorted = (int*)  alloc((size_t)N_EDGES * 4);
    float* alpha8     = (float*)alloc((size_t)N_EDGES * 8 * 4);

    hipMemsetAsync(counts, 0, (size_t)N_NODES * 4, stream);

    k_gemm      <<<(N_NODES + 15) / 16,   256, 0, stream>>>(x, W, b, a, ei, counts,
                                                            h16, s_src, s_dst);
    k_scan1     <<<N_TILES, 1024, 0, stream>>>(counts, row_ptr, blksum);
    k_scan23    <<<(N_NODES + 255) / 256, 256, 0, stream>>>(row_ptr, blksum, cursor);
    k_fill_alpha<<<(N_EDGES + 255) / 256, 256, 0, stream>>>(ei, cursor, s_src, s_dst,
                                                            dst_sorted, alpha8);
    k_gather    <<<(N_NODES + 3) / 4,     256, 0, stream>>>(row_ptr, dst_sorted,
                                                            alpha8, h16, x,
                                                            ln_scale, ln_bias, out);
}